// Round 6
// baseline (17.120 us; speedup 1.0000x reference)
//
#include <hip/hip_runtime.h>

// WKV power kernel, R6: R5 structure + explicit load batching + nontemporal
// stores. 256 blocks x 1 wave; block = dim (uniform -> scalar decay/first
// loads); lane = chunk of L=16 rows; in-wave Kogge-Stone affine scan.

constexpr int T = 1024;
constexpr int D = 256;
constexpr int L = 16;              // rows per lane (64 lanes * 16 = 1024)

__global__ __launch_bounds__(64) void wkv_scan_kernel(
    const float* __restrict__ k, const float* __restrict__ v,
    const float* __restrict__ time_first, const float* __restrict__ time_decay,
    float* __restrict__ out)
{
    const int d    = blockIdx.x;       // dim (uniform across the wave)
    const int lane = threadIdx.x;      // chunk index 0..63

    const float td = time_decay[d];    // block-uniform -> s_load
    const float wd = __expf(td);       // per-row decay
    const float tf = __expf(time_first[d]);

    const int base = lane * L;
    const float* kp = k + base * D + d;
    const float* vp = v + base * D + d;

    // ---- Phase 0: issue ALL 32 scattered loads up front (one latency) ----
    float kx[L], vx[L];
#pragma unroll
    for (int j = 0; j < L; ++j) {
        kx[j] = kp[j * D];
        vx[j] = vp[j * D];
    }

    // ---- Phase 1: local recurrence seeded 0 (kx/vx transformed in place) ----
    float bk = 0.f, bv = 0.f;
#pragma unroll
    for (int j = 0; j < L; ++j) {
        const float e = __expf(kx[j]);
        kx[j] = e;
        vx[j] = vx[j] * e;
        bk = wd * (e + bk);            // s <- w*(x + s)
        bv = wd * (vx[j] + bv);
    }

    // ---- Phase 2: Kogge-Stone inclusive scan across 64 lanes.
    // Chunk multiplier uniform (m = w^L); o-span factor f = m^o, f *= f.
    float f = __expf(td * (float)L);
#pragma unroll
    for (int o = 1; o < 64; o <<= 1) {
        const float pk = __shfl_up(bk, o);
        const float pv = __shfl_up(bv, o);
        if (lane >= o) {
            bk = fmaf(f, pk, bk);
            bv = fmaf(f, pv, bv);
        }
        f = f * f;
    }

    // Exclusive prefix: state entering this lane's chunk.
    float sk = __shfl_up(bk, 1);
    float sv = __shfl_up(bv, 1);
    if (lane == 0) { sk = 0.f; sv = 0.f; }

    // ---- Phase 3: re-run local recurrence seeded with prefix; fused output ----
    float* op = out + base * D + d;
#pragma unroll
    for (int j = 0; j < L; ++j) {
        sk = wd * (kx[j] + sk);                 // = kxr[i]
        sv = wd * (vx[j] + sv);                 // = vxr[i]
        const float num = fmaf(vx[j], tf, sk);  // vx*tf + kxr (faithful swap)
        const float den = fmaf(kx[j], tf, sv);  // kx*tf + vxr
        __builtin_nontemporal_store(num * __builtin_amdgcn_rcpf(den), &op[j * D]);
    }
}

extern "C" void kernel_launch(void* const* d_in, const int* in_sizes, int n_in,
                              void* d_out, int out_size, void* d_ws, size_t ws_size,
                              hipStream_t stream) {
    const float* k  = (const float*)d_in[0];
    const float* v  = (const float*)d_in[1];
    const float* tf = (const float*)d_in[2];
    const float* td = (const float*)d_in[3];
    float* out = (float*)d_out;

    dim3 grid(D);                  // 256 blocks: one dim each -> all 256 CUs
    dim3 block(64);                // 1 wave per block
    wkv_scan_kernel<<<grid, block, 0, stream>>>(k, v, tf, td, out);
}

// Round 7
// 10.026 us; speedup vs baseline: 1.7075x; 1.7075x over previous
//
#include <hip/hip_runtime.h>

// WKV power kernel, R7: single dispatch, 16 blocks x 1024 threads (16 waves).
// Block = 16 dims (one full 64B line width) -> every global access touches
// fully-used lines (4 lines per wave-instr instead of 64 sparse lines).
// Thread (c,dd): dd = t&15 dim-in-block, c = t>>4 chunk of 16 rows.
// Scan: per-chunk affine carries via padded LDS; wave w scans dim w's 64
// carries with the in-wave Kogge-Stone (identical math to R5).

constexpr int T  = 1024;
constexpr int D  = 256;
constexpr int GD = 16;        // dims per block = one 64B line
constexpr int RT = 16;        // rows per thread
constexpr int NCH = T / RT;   // 64 chunks per dim
constexpr int NTH = NCH * GD; // 1024 threads = 16 waves

__global__ __launch_bounds__(NTH) void wkv_scan_kernel(
    const float* __restrict__ k, const float* __restrict__ v,
    const float* __restrict__ time_first, const float* __restrict__ time_decay,
    float* __restrict__ out)
{
    __shared__ float cK[NCH][GD + 1];   // +1 pad: scan reads column-wise
    __shared__ float cV[NCH][GD + 1];

    const int t  = threadIdx.x;
    const int dd = t & (GD - 1);
    const int c  = t >> 4;              // chunk 0..63
    const int d  = blockIdx.x * GD + dd;

    const float td = time_decay[d];
    const float wd = __expf(td);        // per-row decay

    // ---- Phase 1: coalesced load + local recurrence seeded 0 ----
    const int base = c * RT;
    float kx[RT], vx[RT];
    float bk = 0.f, bv = 0.f;
#pragma unroll
    for (int j = 0; j < RT; ++j) {
        const float kk = k[(base + j) * D + d];   // 4 fully-used lines/instr
        const float vv = v[(base + j) * D + d];
        const float e  = __expf(kk);
        kx[j] = e;
        vx[j] = vv * e;
        bk = wd * (e + bk);             // s <- w*(x + s)
        bv = wd * (vx[j] + bv);
    }
    cK[c][dd] = bk;
    cV[c][dd] = bv;
    __syncthreads();

    // ---- Phase 2: wave w scans dim (blk*16 + w); lane = chunk ----
    {
        const int w    = t >> 6;        // wave id 0..15 == dim-in-block
        const int lane = t & 63;
        const float tdw = time_decay[blockIdx.x * GD + w];  // wave-uniform

        float sbk = cK[lane][w];        // stride-17 floats: 2-way bank = free
        float sbv = cV[lane][w];

        // Kogge-Stone inclusive; uniform chunk multiplier m = w^RT,
        // o-span factor f = m^o (f *= f each step).
        float f = __expf(tdw * (float)RT);
#pragma unroll
        for (int o = 1; o < 64; o <<= 1) {
            const float pk = __shfl_up(sbk, o);
            const float pv = __shfl_up(sbv, o);
            if (lane >= o) {
                sbk = fmaf(f, pk, sbk);
                sbv = fmaf(f, pv, sbv);
            }
            f = f * f;
        }
        // Exclusive prefix = state entering chunk `lane`; write back in place
        // (each wave touches only its own column w -> no cross-wave hazard).
        float ek = __shfl_up(sbk, 1);
        float ev = __shfl_up(sbv, 1);
        if (lane == 0) { ek = 0.f; ev = 0.f; }
        cK[lane][w] = ek;
        cV[lane][w] = ev;
    }
    __syncthreads();

    // ---- Phase 3: seed with prefix; reuse register kx/vx; fused output ----
    const float tf = __expf(time_first[d]);
    float sk = cK[c][dd];
    float sv = cV[c][dd];
#pragma unroll
    for (int j = 0; j < RT; ++j) {
        sk = wd * (kx[j] + sk);                 // = kxr[i]
        sv = wd * (vx[j] + sv);                 // = vxr[i]
        const float num = fmaf(vx[j], tf, sk);  // vx*tf + kxr (faithful swap)
        const float den = fmaf(kx[j], tf, sv);  // kx*tf + vxr
        out[(base + j) * D + d] = num * __builtin_amdgcn_rcpf(den);  // coalesced
    }
}

extern "C" void kernel_launch(void* const* d_in, const int* in_sizes, int n_in,
                              void* d_out, int out_size, void* d_ws, size_t ws_size,
                              hipStream_t stream) {
    const float* k  = (const float*)d_in[0];
    const float* v  = (const float*)d_in[1];
    const float* tf = (const float*)d_in[2];
    const float* td = (const float*)d_in[3];
    float* out = (float*)d_out;

    dim3 grid(D / GD);             // 16 blocks, 16 dims each
    dim3 block(NTH);               // 1024 threads = 16 waves
    wkv_scan_kernel<<<grid, block, 0, stream>>>(k, v, tf, td, out);
}